// Round 6
// baseline (1125.516 us; speedup 1.0000x reference)
//
#include <hip/hip_runtime.h>

typedef __bf16 bf16;
typedef __attribute__((ext_vector_type(2))) __bf16 bf16x2;
typedef __attribute__((ext_vector_type(4))) __bf16 bf16x4;
typedef __attribute__((ext_vector_type(8))) __bf16 bf16x8;
typedef __attribute__((ext_vector_type(4))) float f32x4;

#define DEVINL __device__ __forceinline__

typedef __attribute__((address_space(1))) void gvoid_t;
typedef __attribute__((address_space(3))) void lvoid_t;

DEVINL void async_ld16(const void* g, void* l) {
    __builtin_amdgcn_global_load_lds((gvoid_t*)g, (lvoid_t*)l, 16, 0, 0);
}

DEVINL void wait_vm6()   { asm volatile("s_waitcnt vmcnt(6)" ::: "memory"); }
DEVINL void wait_vm4()   { asm volatile("s_waitcnt vmcnt(4)" ::: "memory"); }
DEVINL void wait_vm0()   { asm volatile("s_waitcnt vmcnt(0)" ::: "memory"); }
DEVINL void wait_lgkm0() { asm volatile("s_waitcnt lgkmcnt(0)" ::: "memory");
                           __builtin_amdgcn_sched_barrier(0); }
DEVINL void barrier_()   { __builtin_amdgcn_s_barrier();
                           __builtin_amdgcn_sched_barrier(0); }

// ============================================================================
// 8-wave 256x256 tile GEMM with 4-phase counted-vmcnt pipeline (T3+T4+T5).
// BK=64, 512 threads = 8 waves (2M x 4N), per-wave C = 128x64.
// LDS = 8 half-slots x 16KB = 128 KB:
//   slot s = (t&1)*4 + kind, kind: 0=A rows[0,128), 1=A rows[128,256),
//                                  2=B rows[0,128), 3=B rows[128,256)
// Each half-slot: [128 rows][8 granules of 16B], XOR-swizzled:
//   LDS (r, g) holds global granule g ^ (r&7)  (conflict-free ds_read_b128).
// Schedule per K-tile t (phases q0..q3), stages for tile t+1 issued 1/phase:
//   q0: STAGE(t+1,A0); vmcnt(6); BAR; ld A(k0); lgkm0; MFMA(t-1,k1,Mlo); BAR
//   q1: STAGE(t+1,A1); vmcnt(4); BAR; ld B(k0); lgkm0; MFMA(t-1,k1,Mhi); BAR
//   q2: STAGE(t+1,B0);           BAR; ld A(k1); lgkm0; MFMA(t,  k0,Mlo); BAR
//   q3: STAGE(t+1,B1);           BAR; ld B(k1); lgkm0; MFMA(t,  k0,Mhi); BAR
// vmcnt(6) leaves {t.B0,t.B1,t+1.A0} in flight -> all of tile t's A landed;
// vmcnt(4) leaves {t+1.A0,t+1.A1} -> tile t's B landed. In-flight LDS writes
// always target the opposite dbuf parity from concurrent ds_reads (safe).
// Last iteration: stages vanish -> allowances shrink to 4 / 0.
// MODE 0: A gathered from obj/pred via edges (K=1536, S|P|O), out -> Dbf
// MODE 1: split by global col: <512 -> Dbf(new_s); <1024 -> Df(f32); else Dbf2
// Epilogue staged through LDS (proven full-line-write scheme from r4).
// ============================================================================
template<int MODE>
__global__ __launch_bounds__(512, 2) void gemm8_k(
    const bf16* __restrict__ A, const bf16* __restrict__ Bt,
    const float* __restrict__ bias, bf16* __restrict__ Dbf,
    float* __restrict__ Df, bf16* __restrict__ Dbf2,
    const int* __restrict__ edges, const bf16* __restrict__ obj,
    const bf16* __restrict__ pred, int K, int NBN)
{
    const int tid = threadIdx.x;
    const int id = blockIdx.x;
    const int bn = (id >> 3) % NBN;
    const int bm = (id & 7) + 8 * ((id >> 3) / NBN);

    __shared__ __align__(16) bf16 lds[8 * 8192];   // 128 KiB

    const int g_slot = tid & 7;
    const int row0 = tid >> 3;   // 0..63

    // per-thread rows covered: hi = h*2+i -> row (h*128 + i*64 + row0)
    unsigned offS[4], offP[4], offO[4], offA[4], offB[4];
#pragma unroll
    for (int hi = 0; hi < 4; hi++) {
        int r = (hi >> 1) * 128 + (hi & 1) * 64 + row0;
        int gr = bm * 256 + r;
        if (MODE == 0) {
            int b = gr >> 9;  // T = 512
            int s = edges[gr * 3 + 0] & 255;
            int o = edges[gr * 3 + 2] & 255;
            offS[hi] = (unsigned)(b * 256 + s) * 512u;
            offP[hi] = (unsigned)gr * 512u;
            offO[hi] = (unsigned)(b * 256 + o) * 512u;
        } else {
            offA[hi] = (unsigned)gr * (unsigned)K;
        }
        offB[hi] = (unsigned)(bn * 256 + r) * (unsigned)K;
    }

    auto STAGE = [&](int tt, int kind) {
        bf16* ldst = lds + ((tt & 1) * 4 + kind) * 8192;
        int h = kind & 1;
#pragma unroll
        for (int i = 0; i < 2; i++) {
            int r = i * 64 + row0;
            int gsrc = g_slot ^ (r & 7);
            int hi = h * 2 + i;
            const bf16* gp;
            if (kind < 2) {
                if (MODE == 0) {
                    int region = tt >> 3;  // uniform
                    unsigned col = (unsigned)((tt & 7) * 64 + gsrc * 8);
                    if (region == 0)      gp = obj + offS[hi] + col;
                    else if (region == 1) gp = pred + offP[hi] + col;
                    else                  gp = obj + offO[hi] + col;
                } else {
                    gp = A + offA[hi] + (unsigned)(tt * 64 + gsrc * 8);
                }
            } else {
                gp = Bt + offB[hi] + (unsigned)(tt * 64 + gsrc * 8);
            }
            async_ld16(gp, ldst + (tid + i * 512) * 8);
        }
    };

    f32x4 acc[8][4];
    const f32x4 zero4 = {0.f, 0.f, 0.f, 0.f};
#pragma unroll
    for (int i = 0; i < 8; i++)
#pragma unroll
        for (int j = 0; j < 4; j++) acc[i][j] = zero4;

    const int wave = tid >> 6, lane = tid & 63;
    const int wm = wave >> 2, wn = wave & 3;
    const int lq = lane >> 4, lr = lane & 15;

    bf16x8 af0[8], af1[8], b0r[4], b1r[4];

    auto LDA = [&](int tt, int ks, bf16x8* d) {
        const bf16* base = lds + ((tt & 1) * 4 + wm) * 8192;
#pragma unroll
        for (int mi = 0; mi < 8; mi++) {
            int rr = mi * 16 + lr;
            int g = (ks * 4 + lq) ^ (rr & 7);
            d[mi] = *(const bf16x8*)(base + (rr * 8 + g) * 8);
        }
    };
    auto LDB = [&](int tt, int ks, bf16x8* d) {
        const bf16* base = lds + ((tt & 1) * 4 + 2 + (wn >> 1)) * 8192;
#pragma unroll
        for (int ni = 0; ni < 4; ni++) {
            int rr = (wn & 1) * 64 + ni * 16 + lr;
            int g = (ks * 4 + lq) ^ (rr & 7);
            d[ni] = *(const bf16x8*)(base + (rr * 8 + g) * 8);
        }
    };
    auto MM = [&](const bf16x8* a, const bf16x8* b, int mh) {
        __builtin_amdgcn_s_setprio(1);
#pragma unroll
        for (int mi = 0; mi < 4; mi++)
#pragma unroll
            for (int ni = 0; ni < 4; ni++)
                acc[mh * 4 + mi][ni] = __builtin_amdgcn_mfma_f32_16x16x32_bf16(
                    b[ni], a[mh * 4 + mi], acc[mh * 4 + mi][ni], 0, 0, 0);
        __builtin_amdgcn_s_setprio(0);
        __builtin_amdgcn_sched_barrier(0);
    };

    // prologue: stage tile 0 (4 halves, 8 loads)
    STAGE(0, 0); STAGE(0, 1); STAGE(0, 2); STAGE(0, 3);

    const int NT = K >> 6;
    for (int t = 0; ; ++t) {
        // ---- q0 ----
        if (t < NT) {
            if (t + 1 < NT) { STAGE(t + 1, 0); wait_vm6(); }
            else            wait_vm4();
        } else wait_vm0();
        barrier_();
        if (t < NT) LDA(t, 0, af0);
        wait_lgkm0();
        if (t >= 1) MM(af1, b1r, 0);
        barrier_();
        // ---- q1 ----
        if (t < NT) {
            if (t + 1 < NT) { STAGE(t + 1, 1); wait_vm4(); }
            else            wait_vm0();
        }
        barrier_();
        if (t < NT) LDB(t, 0, b0r);
        wait_lgkm0();
        if (t >= 1) MM(af1, b1r, 1);
        barrier_();
        if (t == NT) break;
        // ---- q2 ----
        if (t + 1 < NT) STAGE(t + 1, 2);
        barrier_();
        LDA(t, 1, af1);
        wait_lgkm0();
        MM(af0, b0r, 0);
        barrier_();
        // ---- q3 ----
        if (t + 1 < NT) STAGE(t + 1, 3);
        barrier_();
        LDB(t, 1, b1r);
        wait_lgkm0();
        MM(af0, b0r, 1);
        barrier_();
    }

    // ---- epilogue via per-wave LDS C-staging (16 KB/wave, disjoint) ----
    const int rowbase = bm * 256 + wm * 128;
    const int cb0 = bn * 256 + wn * 64;
    const bool f32p = (MODE == 1) && (cb0 >= 512) && (cb0 < 1024);

    if (!f32p) {
        bf16* cw = lds + wave * 8192;   // [128 rows][64 cols] bf16
        bf16* outp; int cb;
        if (MODE == 1) {
            if (cb0 < 512) { outp = Dbf;  cb = cb0; }
            else           { outp = Dbf2; cb = cb0 - 1024; }
        } else { outp = Dbf; cb = cb0; }
#pragma unroll
        for (int ni = 0; ni < 4; ++ni) {
            const f32x4 bv = *(const f32x4*)(bias + cb0 + ni * 16 + lq * 4);
#pragma unroll
            for (int mi = 0; mi < 8; ++mi) {
                f32x4 v = acc[mi][ni];
                int row = mi * 16 + lr;
                int sl = (ni * 2 + (lq >> 1)) ^ (row & 7);
                bf16x4 o4;
#pragma unroll
                for (int r = 0; r < 4; r++) {
                    float x = v[r] + bv[r];
                    o4[r] = (bf16)(x > 0.f ? x : 0.f);
                }
                *(bf16x4*)(cw + row * 64 + sl * 8 + (lq & 1) * 4) = o4;
            }
        }
#pragma unroll
        for (int it = 0; it < 16; ++it) {
            int g = it * 64 + lane;
            int row = g >> 3, k = g & 7;
            bf16x8 v = *(const bf16x8*)(cw + row * 64 + ((k ^ (row & 7)) * 8));
            *(bf16x8*)(outp + (unsigned)(rowbase + row) * 512u + cb + k * 8) = v;
        }
    } else {
        float* cwf = (float*)lds + wave * 4096;   // [64 rows][64 cols] f32
        const int cbf = cb0 - 512;
#pragma unroll
        for (int mh = 0; mh < 2; ++mh) {
#pragma unroll
            for (int ni = 0; ni < 4; ++ni) {
                const f32x4 bv = *(const f32x4*)(bias + cb0 + ni * 16 + lq * 4);
#pragma unroll
                for (int mi2 = 0; mi2 < 4; ++mi2) {
                    f32x4 v = acc[mh * 4 + mi2][ni];
                    int row = mi2 * 16 + lr;   // 0..63
                    int s16 = ni * 4 + lq;
                    int sl = (s16 & 8) | ((s16 & 7) ^ (row & 7));
                    f32x4 x;
#pragma unroll
                    for (int r = 0; r < 4; r++) {
                        float tt = v[r] + bv[r];
                        x[r] = tt > 0.f ? tt : 0.f;
                    }
                    *(f32x4*)(cwf + row * 64 + sl * 4) = x;
                }
            }
#pragma unroll
            for (int it = 0; it < 16; ++it) {
                int g = it * 64 + lane;
                int row = g >> 4, k = g & 15;
                int kk = (k & 8) | ((k & 7) ^ (row & 7));
                f32x4 v = *(const f32x4*)(cwf + row * 64 + kk * 4);
                *(f32x4*)(Df + (unsigned)(rowbase + mh * 64 + row) * 512u
                          + cbf + k * 4) = v;
            }
        }
    }
}

// ============================================================================
// Verified 128x128 4-wave kernel (round-4), kept for the small gemms 3/4.
// MODE 2: plain -> Dbf.  MODE 3: plain -> Df (f32)
// ============================================================================
template<int MODE, int NBN>
__global__ __launch_bounds__(256, 2) void gemm_k(
    const bf16* __restrict__ A, const bf16* __restrict__ Bt,
    const float* __restrict__ bias, bf16* __restrict__ Dbf,
    float* __restrict__ Df, int K)
{
    const int tid = threadIdx.x;
    const int id = blockIdx.x;
    const int bn = (id >> 3) % NBN;
    const int bm = (id & 7) + 8 * ((id >> 3) / NBN);

    __shared__ __align__(16) bf16 lds[2 * 128 * 64];
    bf16* ldsA = lds;
    bf16* ldsB = lds + 128 * 64;

    const int g_slot = tid & 7;
    const int row0 = tid >> 3;

    unsigned offA[4], offB[4];
#pragma unroll
    for (int i = 0; i < 4; i++) {
        int r = row0 + 32 * i;
        offA[i] = (unsigned)(bm * 128 + r) * (unsigned)K;
        offB[i] = (unsigned)(bn * 128 + r) * (unsigned)K;
    }

    f32x4 acc[4][4];
    const f32x4 zero4 = {0.f, 0.f, 0.f, 0.f};
#pragma unroll
    for (int i = 0; i < 4; i++)
#pragma unroll
        for (int j = 0; j < 4; j++) acc[i][j] = zero4;

    const int wave = tid >> 6;
    const int lane = tid & 63;
    const int wr = (wave >> 1) * 64;
    const int wc = (wave & 1) * 64;
    const int lq = lane >> 4;
    const int lr = lane & 15;

    const int KT = K >> 6;
    for (int kt = 0; kt < KT; ++kt) {
        __syncthreads();
#pragma unroll
        for (int i = 0; i < 4; i++) {
            int r = row0 + 32 * i;
            int gsrc = g_slot ^ (r & 7);
            async_ld16(A + offA[i] + (unsigned)(kt * 64 + gsrc * 8),
                       ldsA + (tid + i * 256) * 8);
        }
#pragma unroll
        for (int i = 0; i < 4; i++) {
            int r = row0 + 32 * i;
            int gsrc = g_slot ^ (r & 7);
            async_ld16(Bt + offB[i] + (unsigned)(kt * 64 + gsrc * 8),
                       ldsB + (tid + i * 256) * 8);
        }
        __syncthreads();

#pragma unroll
        for (int ks = 0; ks < 2; ++ks) {
            bf16x8 af[4], bfr[4];
#pragma unroll
            for (int mi = 0; mi < 4; ++mi) {
                int r = wr + mi * 16 + lr;
                int g = (ks * 4 + lq) ^ (r & 7);
                af[mi] = *(const bf16x8*)(ldsA + (r * 8 + g) * 8);
            }
#pragma unroll
            for (int ni = 0; ni < 4; ++ni) {
                int r = wc + ni * 16 + lr;
                int g = (ks * 4 + lq) ^ (r & 7);
                bfr[ni] = *(const bf16x8*)(ldsB + (r * 8 + g) * 8);
            }
#pragma unroll
            for (int mi = 0; mi < 4; ++mi)
#pragma unroll
                for (int ni = 0; ni < 4; ++ni)
                    acc[mi][ni] = __builtin_amdgcn_mfma_f32_16x16x32_bf16(
                        bfr[ni], af[mi], acc[mi][ni], 0, 0, 0);
        }
    }

    __syncthreads();
    const int rb = bm * 128 + wr;

    if (MODE == 2) {
        bf16* cw = lds + wave * 4096;
        const int cb = bn * 128 + wc;
#pragma unroll
        for (int ni = 0; ni < 4; ++ni) {
            const f32x4 bv = *(const f32x4*)(bias + cb + ni * 16 + lq * 4);
#pragma unroll
            for (int mi = 0; mi < 4; ++mi) {
                f32x4 v = acc[mi][ni];
                int row = mi * 16 + lr;
                int sl = (ni * 2 + (lq >> 1)) ^ (row & 7);
                bf16x4 o4;
#pragma unroll
                for (int r = 0; r < 4; r++) {
                    float t = v[r] + bv[r];
                    o4[r] = (bf16)(t > 0.f ? t : 0.f);
                }
                *(bf16x4*)(cw + row * 64 + sl * 8 + (lq & 1) * 4) = o4;
            }
        }
#pragma unroll
        for (int it = 0; it < 8; ++it) {
            int g = it * 64 + lane;
            int row = g >> 3, k = g & 7;
            bf16x8 v = *(const bf16x8*)(cw + row * 64 + ((k ^ (row & 7)) * 8));
            *(bf16x8*)(Dbf + (unsigned)(rb + row) * 512u + cb + k * 8) = v;
        }
    } else {
        float* cwf = (float*)lds + wave * 2048;
        const int cbf = bn * 128 + wc;
#pragma unroll
        for (int half = 0; half < 2; ++half) {
#pragma unroll
            for (int ni = 0; ni < 4; ++ni) {
                const f32x4 bv = *(const f32x4*)(bias + cbf + ni * 16 + lq * 4);
#pragma unroll
                for (int mi2 = 0; mi2 < 2; ++mi2) {
                    f32x4 v = acc[half * 2 + mi2][ni];
                    int row = mi2 * 16 + lr;
                    int s16 = ni * 4 + lq;
                    int sl = (s16 & 8) | ((s16 & 7) ^ (row & 7));
                    f32x4 x;
#pragma unroll
                    for (int r = 0; r < 4; r++) {
                        float t = v[r] + bv[r];
                        x[r] = t > 0.f ? t : 0.f;
                    }
                    *(f32x4*)(cwf + row * 64 + sl * 4) = x;
                }
            }
#pragma unroll
            for (int it = 0; it < 8; ++it) {
                int g = it * 64 + lane;
                int row = g >> 4, k = g & 15;
                int kk = (k & 8) | ((k & 7) ^ (row & 7));
                f32x4 v = *(const f32x4*)(cwf + row * 64 + kk * 4);
                *(f32x4*)(Df + (unsigned)(rb + half * 32 + row) * 512u + cbf + k * 4) = v;
            }
        }
    }
}

// Fused preprocessing: cvt obj/pred f32->bf16 + 4 weight transposes
__global__ void pre_k(const float4* __restrict__ o, const float4* __restrict__ p,
                      bf16x4* __restrict__ ob, bf16x4* __restrict__ pb,
                      const float* __restrict__ w1, bf16* __restrict__ w1t,
                      const float* __restrict__ w2, bf16* __restrict__ w2t,
                      const float* __restrict__ w3, bf16* __restrict__ w3t,
                      const float* __restrict__ w4, bf16* __restrict__ w4t) {
    __shared__ float tile[32][33];
    int blk = blockIdx.x;
    int t = threadIdx.x;
    if (blk >= 24576) {
        int id = blk - 24576;
        const float* src; bf16* dst; int R, C, bx, by;
        if (id < 768)       { src = w1; dst = w1t; R = 1536; C = 512;  bx = id % 16; by = id / 16; }
        else if (id < 1536) { id -= 768;  src = w2; dst = w2t; R = 512; C = 1536; bx = id % 48; by = id / 48; }
        else if (id < 1792) { id -= 1536; src = w3; dst = w3t; R = 512; C = 512;  bx = id % 16; by = id / 16; }
        else                { id -= 1792; src = w4; dst = w4t; R = 512; C = 512;  bx = id % 16; by = id / 16; }
        int c0 = bx * 32, r0 = by * 32;
        int tx = t & 31, ty = t >> 5;
#pragma unroll
        for (int i = 0; i < 4; i++)
            tile[ty + i * 8][tx] = src[(size_t)(r0 + ty + i * 8) * C + c0 + tx];
        __syncthreads();
#pragma unroll
        for (int i = 0; i < 4; i++)
            dst[(size_t)(c0 + ty + i * 8) * R + r0 + tx] = (bf16)tile[tx][ty + i * 8];
        return;
    }
    int i = blk * 256 + t;
    if (i < 2097152) {
        float4 v = o[i];
        bf16x4 r = { (bf16)v.x, (bf16)v.y, (bf16)v.z, (bf16)v.w };
        ob[i] = r;
    } else {
        int j = i - 2097152;
        float4 v = p[j];
        bf16x4 r = { (bf16)v.x, (bf16)v.y, (bf16)v.z, (bf16)v.w };
        pb[j] = r;
    }
}

// Self-contained scatter-mean pooling (one block per (b,n))
__global__ __launch_bounds__(256) void pool3_k(
    const int* __restrict__ edges,
    const bf16* __restrict__ new_s, const bf16* __restrict__ new_o,
    bf16* __restrict__ out)
{
    __shared__ int ent[1024];
    __shared__ int ec;
    const int idx = blockIdx.x;
    const int b = idx >> 8, n = idx & 255;
    const int t = threadIdx.x;
    if (t == 0) ec = 0;
    __syncthreads();
#pragma unroll
    for (int e0 = 0; e0 < 2; e0++) {
        int row = b * 512 + t + e0 * 256;
        int s = edges[row * 3 + 0] & 255;
        int o = edges[row * 3 + 2] & 255;
        if (s == n) { int ps = atomicAdd(&ec, 1); ent[ps] = row << 1; }
        if (o == n) { int po = atomicAdd(&ec, 1); ent[po] = (row << 1) | 1; }
    }
    __syncthreads();
    const int c = ec;
    float a0 = 0.f, a1 = 0.f;
    for (int j = 0; j < c; ++j) {
        int v = ent[j];
        const bf16x2* rp = (const bf16x2*)(((v & 1) ? new_o : new_s) +
                                           (unsigned)(v >> 1) * 512u);
        bf16x2 w = rp[t];
        a0 += (float)w[0];
        a1 += (float)w[1];
    }
    float inv = 1.f / (float)(c > 1 ? c : 1);
    bf16x2 o2 = { (bf16)(a0 * inv), (bf16)(a1 * inv) };
    *(bf16x2*)(out + (unsigned)idx * 512u + (unsigned)(t * 2)) = o2;
}

extern "C" void kernel_launch(void* const* d_in, const int* in_sizes, int n_in,
                              void* d_out, int out_size, void* d_ws, size_t ws_size,
                              hipStream_t stream) {
    const float* obj_f  = (const float*)d_in[0];
    const float* pred_f = (const float*)d_in[1];
    const int*   edges  = (const int*)d_in[2];
    const float* w1 = (const float*)d_in[3];
    const float* b1 = (const float*)d_in[4];
    const float* w2 = (const float*)d_in[5];
    const float* b2 = (const float*)d_in[6];
    const float* w3 = (const float*)d_in[7];
    const float* b3 = (const float*)d_in[8];
    const float* w4 = (const float*)d_in[9];
    const float* b4 = (const float*)d_in[10];

    // workspace layout — 88 MB
    char* ws = (char*)d_ws;
    bf16* obj_bf  = (bf16*)(ws + 0);            // 16 MB   [dead after gemm1]
    bf16* pred_bf = (bf16*)(ws + 16777216);     // 32 MB   [dead after gemm1]
    bf16* new_s   = (bf16*)(ws + 0);            // 32 MB   overlays obj/pred
    bf16* w1t = (bf16*)(ws + 50331648);         // 512 x 1536
    bf16* w2t = (bf16*)(ws + 51904512);         // 1536 x 512
    bf16* w3t = (bf16*)(ws + 53477376);         // 512 x 512
    bf16* w4t = (bf16*)(ws + 54001664);         // 512 x 512
    bf16* hid = (bf16*)(ws + 54525952);         // 32768 x 512 (32 MB)
    bf16* pooled_bf = hid;                      // 16 MB, reuse after gemm2
    bf16* h2  = (bf16*)(ws + 71303168);         // 16 MB

    float* out_obj = (float*)d_out;             // 64*256*512 f32
    float* out_p   = (float*)d_out + 8388608;   // 64*512*512 f32
    bf16* new_o    = (bf16*)d_out;              // scratch; overwritten by gemm4

    pre_k<<<26624, 256, 0, stream>>>((const float4*)obj_f, (const float4*)pred_f,
                                     (bf16x4*)obj_bf, (bf16x4*)pred_bf,
                                     w1, w1t, w2, w2t, w3, w3t, w4, w4t);

    // gemm1: gathered [obj[s]|pred|obj[o]] (K=1536) -> hid   (256x256, 8-phase)
    gemm8_k<0><<<256, 512, 0, stream>>>(
        nullptr, w1t, b1, hid, nullptr, nullptr, edges, obj_bf, pred_bf,
        1536, 2);

    // gemm2: hid @ w2t -> new_s | out_p | new_o              (256x256, 8-phase)
    gemm8_k<1><<<768, 512, 0, stream>>>(
        hid, w2t, b2, new_s, out_p, new_o, nullptr, nullptr, nullptr,
        512, 6);

    pool3_k<<<16384, 256, 0, stream>>>(edges, new_s, new_o, pooled_bf);

    // gemm3: pooled @ w3t -> h2   (128x128 path)
    gemm_k<2, 4><<<512, 256, 0, stream>>>(pooled_bf, w3t, b3, h2, nullptr, 512);

    // gemm4: h2 @ w4t -> out_obj (f32)
    gemm_k<3, 4><<<512, 256, 0, stream>>>(h2, w4t, b4, nullptr, out_obj, 512);
}